// Round 18
// baseline (170.574 us; speedup 1.0000x reference)
//
#include <hip/hip_runtime.h>
#include <hip/hip_bf16.h>

#define N_NODES 100000
#define N_EDGES 640000
#define D_EE 32
#define D_O  128
#define SCAN_CHUNK 1024
#define NB_SCAN ((N_NODES + SCAN_CHUNK - 1) / SCAN_CHUNK)  // 98
#define EPB 64                        // edges per k_edge_mlp block
#define NBLK_E (N_EDGES / EPB)        // 10000
#define EAS 40                        // ea_s row stride in bf16 (80B, 16B-aligned)
#define MTS 72                        // msg_T col stride in bf16 (144B, 16B-aligned)
#define XNS 64                        // nodes per k_node block
#define XRS 136                       // x_s row stride in bf16 (272B, 16B-aligned)
#define NBLK_N ((N_NODES + XNS - 1) / XNS)   // 1563
#define NBLK_H 2500                   // hist blocks in fused kernel

typedef unsigned short u16;
typedef unsigned int u32;
typedef unsigned char u8;
typedef short bf16x8 __attribute__((ext_vector_type(8)));
typedef float f32x4 __attribute__((ext_vector_type(4)));

// ---------- helpers (hardware RNE bf16 converts; memcpy-safe bit extract) ----------
__device__ __forceinline__ u16 f2bf(float f) {
    __hip_bfloat16 h = __float2bfloat16(f);
    u16 r;
    __builtin_memcpy(&r, &h, 2);
    return r;
}
__device__ __forceinline__ u32 f2bf2(float a, float b) {
    __hip_bfloat162 h = __float22bfloat162_rn(make_float2(a, b));
    u32 r;
    __builtin_memcpy(&r, &h, 4);
    return r;
}
__device__ __forceinline__ float bf2f(u16 u) {
    return __uint_as_float((u32)u << 16);
}
// fast sigmoid*rb: rb * rcp(1+e^-x); v_rcp_f32 ~1ulp, output <=0.1, thr 2e-3
__device__ __forceinline__ float sigrb(float x, float rb) {
    return rb * __builtin_amdgcn_rcpf(1.f + __expf(-x));
}
// int64 little-endian node ids < 2^31 => every odd int32 word is 0.
__device__ __forceinline__ int detect32(const int* __restrict__ ei) {
    int o = 0;
#pragma unroll
    for (int i = 1; i < 64; i += 2) o |= ei[i];
    return o != 0;  // 1 => int32, 0 => int64
}

// ---------- K0: fold weights -> fragment-packed bf16 + bias c; extra blocks zero ----------
__global__ __launch_bounds__(256) void k_fold_zero(
    const float* __restrict__ Wx, const float* __restrict__ bx,
    const float* __restrict__ We, const float* __restrict__ be,
    const float* __restrict__ Wm, const float* __restrict__ bm,
    u16* __restrict__ Afrag, u16* __restrict__ Bfrag, float* __restrict__ c,
    float4* __restrict__ zbase, int zn4) {
    int b = blockIdx.x;
    if (b >= 81) {   // zero phase: blocks 81.. zero counts+cursor+flags
        int i = (b - 81) * 256 + threadIdx.x;
        int stride = (gridDim.x - 81) * 256;
        float4 z = make_float4(0.f, 0.f, 0.f, 0.f);
        for (; i < zn4; i += stride) zbase[i] = z;
        return;
    }
    int idx = b * 256 + threadIdx.x;
    if (idx < 16384) {
        int i = idx >> 7, j = idx & 127;
        float s = 0.f;
        for (int k = 0; k < 128; ++k) s = fmaf(Wx[i * 128 + k], Wm[k * 128 + j], s);
        int ks = i >> 5, r = i & 31, l4 = r >> 3, jj = r & 7;
        int ct = j >> 4, l15 = j & 15;
        Afrag[(ks * 8 + ct) * 512 + (l4 * 16 + l15) * 8 + jj] = f2bf(s);
    } else if (idx < 16384 + 4096) {
        int t = idx - 16384;
        int i = t >> 7, j = t & 127;
        float s = 0.f;
        for (int k = 0; k < 128; ++k) s = fmaf(We[i * 128 + k], Wm[(128 + k) * 128 + j], s);
        int l4 = i >> 3, jj = i & 7, ct = j >> 4, l15 = j & 15;
        Bfrag[ct * 512 + (l4 * 16 + l15) * 8 + jj] = f2bf(s);
    } else if (idx < 16384 + 4096 + 128) {
        int j = idx - 20480;
        float s = bm[j];
        for (int k = 0; k < 128; ++k) s = fmaf(bx[k], Wm[k * 128 + j], s);
        for (int k = 0; k < 128; ++k) s = fmaf(be[k], Wm[(128 + k) * 128 + j], s);
        c[j] = s;
    }
}

// ---------- K1: fused hist (blocks 0..2499) + node GEMM (blocks 2500..) ----------
__global__ __launch_bounds__(256, 4) void k_hist_node(
    const void* __restrict__ ei_raw, int* __restrict__ counts,
    const float* __restrict__ x, const u16* __restrict__ Afrag,
    const float* __restrict__ c, u16* __restrict__ n2b) {
    __shared__ u16 x_s[XNS * XRS];
    int b = blockIdx.x;
    int tid = threadIdx.x;
    if (b < NBLK_H) {   // ---- hist ----
        int e = b * 256 + tid;
        if (e >= N_EDGES) return;
        int dst;
        if (detect32((const int*)ei_raw)) {
            dst = ((const int*)ei_raw)[N_EDGES + e];
        } else {
            dst = (int)((const long long*)ei_raw)[N_EDGES + e];
        }
        atomicAdd(&counts[dst], 1);
        return;
    }
    // ---- node GEMM (r16-proven) ----
    int nb = (b - NBLK_H) * XNS;
    {
        int row = tid >> 2, q = tid & 3;
        int node = nb + row;
        u16* wp = &x_s[row * XRS + q * 32];
        if (node < N_NODES) {
            const float4* src = (const float4*)(x + (size_t)node * 128 + q * 32);
#pragma unroll
            for (int i = 0; i < 8; ++i) {
                float4 v = src[i];
                *(uint2*)(wp + i * 4) =
                    make_uint2(f2bf2(v.x, v.y), f2bf2(v.z, v.w));
            }
        } else {
#pragma unroll
            for (int i = 0; i < 8; ++i)
                *(uint2*)(wp + i * 4) = make_uint2(0u, 0u);
        }
    }
    int lane = tid & 63, wv = tid >> 6;
    int l15 = lane & 15, l4 = lane >> 4;
    f32x4 acc[8];
#pragma unroll
    for (int ct = 0; ct < 8; ++ct) {
        float cv = c[ct * 16 + l15];
        acc[ct] = (f32x4){cv, cv, cv, cv};
    }
    __syncthreads();
    int w16 = wv * 16;
#pragma unroll
    for (int ks = 0; ks < 4; ++ks) {
        bf16x8 af = *(const bf16x8*)(&x_s[(w16 + l15) * XRS + ks * 32 + l4 * 8]);
#pragma unroll
        for (int ct = 0; ct < 8; ++ct) {
            bf16x8 bf = *(const bf16x8*)(Afrag + (size_t)(ks * 8 + ct) * 512 + lane * 8);
            acc[ct] = __builtin_amdgcn_mfma_f32_16x16x32_bf16(af, bf, acc[ct], 0, 0, 0);
        }
    }
    int node0 = nb + w16 + l4 * 4;
#pragma unroll
    for (int ct = 0; ct < 8; ++ct) {
        int col = ct * 16 + l15;
#pragma unroll
        for (int r = 0; r < 4; ++r) {
            int node = node0 + r;
            if (node < N_NODES) n2b[(size_t)node * 128 + col] = f2bf(acc[ct][r]);
        }
    }
}

// ---------- scan A: per-1024-chunk sums ----------
__global__ __launch_bounds__(256) void k_scan_a(
    const int* __restrict__ counts, int* __restrict__ bsum) {
    __shared__ int L[256];
    int b = blockIdx.x, t = threadIdx.x;
    int base = b * SCAN_CHUNK + t * 4;
    int s = 0;
#pragma unroll
    for (int r = 0; r < 4; ++r) {
        int i = base + r;
        if (i < N_NODES) s += counts[i];
    }
    L[t] = s;
    __syncthreads();
    for (int h = 128; h > 0; h >>= 1) {
        if (t < h) L[t] += L[t + h];
        __syncthreads();
    }
    if (t == 0) bsum[b] = L[0];
}

// ---------- scan C (absorbs scan B + boundary-agg zero, 32-edge segments) ----------
// Sweep segments are 32 sorted edges (EPB=64, 2 halves). Node d receives
// atomics iff its run [o, o+c) touches a 32-edge segment boundary.
__global__ __launch_bounds__(256) void k_scan_c(
    const int* __restrict__ counts, const int* __restrict__ bsum,
    int* __restrict__ offsets, float* __restrict__ agg) {
    __shared__ int L[256];
    __shared__ int BS[128];
    int b = blockIdx.x, t = threadIdx.x;
    if (t < NB_SCAN) BS[t] = bsum[t];
    int base = b * SCAN_CHUNK + t * 4;
    int c0 = 0, c1 = 0, c2 = 0, c3 = 0;
    if (base + 0 < N_NODES) c0 = counts[base + 0];
    if (base + 1 < N_NODES) c1 = counts[base + 1];
    if (base + 2 < N_NODES) c2 = counts[base + 2];
    if (base + 3 < N_NODES) c3 = counts[base + 3];
    L[t] = c0 + c1 + c2 + c3;
    __syncthreads();
    if (t == 0) {
        int run = 0;
        for (int i = 0; i < b; ++i) run += BS[i];   // block offset
        for (int i = 0; i < 256; ++i) { int tmp = L[i]; L[i] = run; run += tmp; }
    }
    __syncthreads();
    int o = L[t];
    int oo[4] = {o, o + c0, o + c0 + c1, o + c0 + c1 + c2};
    int cc[4] = {c0, c1, c2, c3};
#pragma unroll
    for (int r = 0; r < 4; ++r) {
        int node = base + r;
        if (node >= N_NODES) break;
        offsets[node] = oo[r];
        int cn = cc[r];
        if (cn > 0) {
            int oe = oo[r] + cn;
            bool bnd = ((oo[r] & 31) == 0) || ((oe & 31) == 0) ||
                       ((oo[r] >> 5) != ((oe - 1) >> 5));
            if (bnd) {
                float4* ap = (float4*)(agg + (size_t)node * 128);
                float4 z = make_float4(0.f, 0.f, 0.f, 0.f);
#pragma unroll
                for (int q = 0; q < 32; ++q) ap[q] = z;
            }
        }
    }
}

// ---------- scatter: perm/src/dst in dst-sorted order ----------
__global__ __launch_bounds__(256) void k_scatter(
    const void* __restrict__ ei_raw, const int* __restrict__ offsets,
    int* __restrict__ cursor, int* __restrict__ perm,
    int* __restrict__ src_s, int* __restrict__ dst_s) {
    int e = blockIdx.x * 256 + threadIdx.x;
    if (e >= N_EDGES) return;
    int src, dst;
    if (detect32((const int*)ei_raw)) {
        src = ((const int*)ei_raw)[e];
        dst = ((const int*)ei_raw)[N_EDGES + e];
    } else {
        src = (int)((const long long*)ei_raw)[e];
        dst = (int)((const long long*)ei_raw)[N_EDGES + e];
    }
    int pos = offsets[dst] + atomicAdd(&cursor[dst], 1);
    perm[pos] = e;
    src_s[pos] = src;
    dst_s[pos] = dst;
}

// ---------- K2: edge MLP, EPB=64, 8 blocks/CU for latency hiding ----------
// Block owns 64 sorted edges; wave wv computes edge-tile wv*16 x 8 col-tiles
// (one MFMA each). LDS union ~19KB -> 8 blocks/CU (launch_bounds(256,8),
// VGPR cap 64). Sweep: 128 cols x 2 halves of 32 edges, 32-edge segments.
__global__ __launch_bounds__(256, 8) void k_edge_mlp(
    const float* __restrict__ ea, const int* __restrict__ perm,
    const int* __restrict__ src_s, const int* __restrict__ dst_s,
    const u16* __restrict__ Bfrag, const u16* __restrict__ n2b,
    float* __restrict__ agg, u8* __restrict__ flags,
    const float* __restrict__ beta, float* __restrict__ out) {
    __shared__ union ShMem {
        u16 ea[EPB * EAS];      // 5120 B (staging phase)
        u16 msg[128 * MTS];     // 18432 B (message phase, col-major)
    } sh;
    __shared__ __align__(16) int src_l[EPB];
    __shared__ __align__(16) int dst_l[EPB];
    int tid = threadIdx.x;
    int base = blockIdx.x * EPB;
    if (tid < EPB) {
        src_l[tid] = src_s[base + tid];
        dst_l[tid] = dst_s[base + tid];
    }
    {   // stage ea rows f32 -> bf16: thread t does row t>>2, 8-float chunk t&3
        int row = tid >> 2, q = tid & 3;
        int p = perm[base + row];
        const float4* s4 = (const float4*)(ea + (size_t)p * 32 + q * 8);
        float4 v0 = s4[0], v1 = s4[1];
        u16* wp = &sh.ea[row * EAS + q * 8];
        *(uint2*)(wp + 0) = make_uint2(f2bf2(v0.x, v0.y), f2bf2(v0.z, v0.w));
        *(uint2*)(wp + 4) = make_uint2(f2bf2(v1.x, v1.y), f2bf2(v1.z, v1.w));
    }
    int lane = tid & 63, wv = tid >> 6;
    int l15 = lane & 15, l4 = lane >> 4;
    bf16x8 bfr[8];
#pragma unroll
    for (int ct = 0; ct < 8; ++ct)
        bfr[ct] = *(const bf16x8*)(Bfrag + ct * 512 + lane * 8);
    float rb = fmaxf(beta[0], 0.f);
    __syncthreads();   // ea + src/dst_l visible
    bf16x8 af = *(const bf16x8*)(&sh.ea[(wv * 16 + l15) * EAS + l4 * 8]);
    // batched n2b gathers (32 per thread)
    u16 nv[8][4];
#pragma unroll
    for (int r = 0; r < 4; ++r) {
        const u16* nr = n2b + (size_t)src_l[wv * 16 + l4 * 4 + r] * 128 + l15;
#pragma unroll
        for (int ct = 0; ct < 8; ++ct) nv[ct][r] = nr[ct * 16];
    }
    __syncthreads();   // all waves done reading sh.ea -> safe to write sh.msg

    int e0 = wv * 16 + l4 * 4;
#pragma unroll
    for (int ct = 0; ct < 8; ++ct) {
        f32x4 acc = {0.f, 0.f, 0.f, 0.f};
        acc = __builtin_amdgcn_mfma_f32_16x16x32_bf16(af, bfr[ct], acc, 0, 0, 0);
        int col = ct * 16 + l15;
        float m0 = acc[0] + bf2f(nv[ct][0]);
        float m1 = acc[1] + bf2f(nv[ct][1]);
        float m2 = acc[2] + bf2f(nv[ct][2]);
        float m3 = acc[3] + bf2f(nv[ct][3]);
        m0 = fmaxf(m0, 0.01f * m0);   // leaky: max(x, 0.01x)
        m1 = fmaxf(m1, 0.01f * m1);
        m2 = fmaxf(m2, 0.01f * m2);
        m3 = fmaxf(m3, 0.01f * m3);
        u32 w01 = f2bf2(m0, m1);
        u32 w23 = f2bf2(m2, m3);
        *(uint2*)(&sh.msg[col * MTS + e0]) = make_uint2(w01, w23);
    }
    __syncthreads();

    int c = tid & 127, h = tid >> 7;
    const u16* mrow = &sh.msg[c * MTS + h * 32];
    const int4* drow = (const int4*)(dst_l + h * 32);
    float acc = 0.f;
    int cur = dst_l[h * 32];
    int nflush = 0;
#pragma unroll 1
    for (int g = 0; g < 4; ++g) {
        bf16x8 mv = *(const bf16x8*)(mrow + g * 8);
        int4 da = drow[g * 2], db = drow[g * 2 + 1];
        int dd[8] = {da.x, da.y, da.z, da.w, db.x, db.y, db.z, db.w};
#pragma unroll
        for (int j = 0; j < 8; ++j) {
            int d = dd[j];
            if (d != cur) {
                if (nflush) {   // run strictly inside segment: node complete
                    out[(size_t)cur * 128 + c] = sigrb(acc, rb);
                    if (c == 0) flags[cur] = 1;
                } else {        // touches segment start
                    unsafeAtomicAdd(agg + (size_t)cur * 128 + c, acc);
                }
                ++nflush;
                acc = 0.f;
                cur = d;
            }
            acc += bf2f((u16)mv[j]);
        }
    }
    unsafeAtomicAdd(agg + (size_t)cur * 128 + c, acc);  // touches segment end
}

// ---------- K3: finish boundary + zero-degree nodes ----------
__global__ __launch_bounds__(256) void k_final(
    const float* __restrict__ agg, const u8* __restrict__ flags,
    const int* __restrict__ counts, const float* __restrict__ beta,
    float4* __restrict__ out) {
    float rb = fmaxf(beta[0], 0.f);
    float hb = 0.5f * rb;
    int i = blockIdx.x * 256 + threadIdx.x;
    int stride = gridDim.x * 256;
    const float4* a4 = (const float4*)agg;
    const int n4 = N_NODES * 32;   // 32 float4 per node
    for (; i < n4; i += stride) {
        int node = i >> 5;
        if (flags[node]) continue;           // interior: out already written
        if (counts[node] == 0) {             // zero-degree: sigmoid(0)*rb
            out[i] = make_float4(hb, hb, hb, hb);
            continue;
        }
        float4 v = a4[i];
        float4 r;
        r.x = sigrb(v.x, rb);
        r.y = sigrb(v.y, rb);
        r.z = sigrb(v.z, rb);
        r.w = sigrb(v.w, rb);
        out[i] = r;
    }
}

// ---------- launch ----------
extern "C" void kernel_launch(void* const* d_in, const int* in_sizes, int n_in,
                              void* d_out, int out_size, void* d_ws, size_t ws_size,
                              hipStream_t stream) {
    const float* x    = (const float*)d_in[0];
    const float* ea   = (const float*)d_in[1];
    const float* Wx   = (const float*)d_in[2];
    const float* bx   = (const float*)d_in[3];
    const float* We   = (const float*)d_in[4];
    const float* be   = (const float*)d_in[5];
    const float* Wm   = (const float*)d_in[6];
    const float* bm   = (const float*)d_in[7];
    const float* beta = (const float*)d_in[8];
    const void*  ei   = d_in[9];

    // ws layout (byte offsets) — r14 layout:
    //   c @0 (512), Bfrag @512 (8192), Afrag @8704 (32768) -> 41472
    //   counts @41472 (400000), cursor @441472 (400000),
    //   flags @841472 (102400), agg @943872 (51200000) -> 52143872
    //   bsum @52143872 (512), offs @52144896 (400000)
    //   perm @52544896, src_s @55104896, dst_s @57664896 (each 2560000)
    //   n2b @60224896 (25600000) -> 85824896
    if (ws_size < (size_t)85824896) return;

    char* ws = (char*)d_ws;
    float* c      = (float*)(ws);
    u16*   Bfrag  = (u16*)(ws + 512);
    u16*   Afrag  = (u16*)(ws + 8704);
    int*   counts = (int*)(ws + 41472);
    int*   cursor = (int*)(ws + 441472);
    u8*    flags  = (u8*)(ws + 841472);
    float* agg    = (float*)(ws + 943872);
    int*   bsum   = (int*)(ws + 52143872);
    int*   offs   = (int*)(ws + 52144896);
    int*   perm   = (int*)(ws + 52544896);
    int*   src_s  = (int*)(ws + 55104896);
    int*   dst_s  = (int*)(ws + 57664896);
    u16*   n2b    = (u16*)(ws + 60224896);

    // fold + zero counts/cursor/flags (902,400 B = 56,400 float4)
    k_fold_zero<<<81 + 256, 256, 0, stream>>>(Wx, bx, We, be, Wm, bm,
                                              Afrag, Bfrag, c,
                                              (float4*)(ws + 41472), 56400);
    // fused: hist (2500 blocks) + node GEMM (1563 blocks)
    k_hist_node<<<NBLK_H + NBLK_N, 256, 0, stream>>>(ei, counts, x, Afrag, c, n2b);
    k_scan_a<<<NB_SCAN, 256, 0, stream>>>(counts, bsum);
    k_scan_c<<<NB_SCAN, 256, 0, stream>>>(counts, bsum, offs, agg);
    k_scatter<<<2500, 256, 0, stream>>>(ei, offs, cursor, perm, src_s, dst_s);
    k_edge_mlp<<<NBLK_E, 256, 0, stream>>>(ea, perm, src_s, dst_s, Bfrag, n2b,
                                           agg, flags, beta, (float*)d_out);
    k_final<<<2048, 256, 0, stream>>>(agg, flags, counts, beta, (float4*)d_out);
}

// Round 19
// 160.861 us; speedup vs baseline: 1.0604x; 1.0604x over previous
//
#include <hip/hip_runtime.h>
#include <hip/hip_bf16.h>

#define N_NODES 100000
#define N_EDGES 640000
#define D_EE 32
#define D_O  128
#define SCAN_CHUNK 1024
#define NB_SCAN ((N_NODES + SCAN_CHUNK - 1) / SCAN_CHUNK)  // 98
#define EPB 128                       // edges per k_edge_mlp block
#define NBLK_E (N_EDGES / EPB)        // 5000
#define EAS 40                        // ea_s row stride in bf16 (80B, 16B-aligned)
#define MTS 136                       // msg_T col stride in bf16 (272B, 16B-aligned)
#define XNS 64                        // nodes per k_node block
#define XRS 136                       // x_s row stride in bf16 (272B, 16B-aligned)
#define NBLK_N ((N_NODES + XNS - 1) / XNS)   // 1563
#define NBLK_H 2500                   // hist blocks in fused kernel

typedef unsigned short u16;
typedef unsigned int u32;
typedef unsigned char u8;
typedef short bf16x8 __attribute__((ext_vector_type(8)));
typedef float f32x4 __attribute__((ext_vector_type(4)));

// ---------- helpers (hardware RNE bf16 converts; memcpy-safe bit extract) ----------
__device__ __forceinline__ u16 f2bf(float f) {
    __hip_bfloat16 h = __float2bfloat16(f);
    u16 r;
    __builtin_memcpy(&r, &h, 2);
    return r;
}
__device__ __forceinline__ u32 f2bf2(float a, float b) {
    __hip_bfloat162 h = __float22bfloat162_rn(make_float2(a, b));
    u32 r;
    __builtin_memcpy(&r, &h, 4);
    return r;
}
__device__ __forceinline__ float bf2f(u16 u) {
    return __uint_as_float((u32)u << 16);
}
// fast sigmoid*rb: rb * rcp(1+e^-x); v_rcp_f32 ~1ulp, output <=0.1, thr 2e-3
__device__ __forceinline__ float sigrb(float x, float rb) {
    return rb * __builtin_amdgcn_rcpf(1.f + __expf(-x));
}
// int64 little-endian node ids < 2^31 => every odd int32 word is 0.
__device__ __forceinline__ int detect32(const int* __restrict__ ei) {
    int o = 0;
#pragma unroll
    for (int i = 1; i < 64; i += 2) o |= ei[i];
    return o != 0;  // 1 => int32, 0 => int64
}

// ---------- K0: fold weights -> fragment-packed bf16 + bias c; extra blocks zero ----------
__global__ __launch_bounds__(256) void k_fold_zero(
    const float* __restrict__ Wx, const float* __restrict__ bx,
    const float* __restrict__ We, const float* __restrict__ be,
    const float* __restrict__ Wm, const float* __restrict__ bm,
    u16* __restrict__ Afrag, u16* __restrict__ Bfrag, float* __restrict__ c,
    float4* __restrict__ zbase, int zn4) {
    int b = blockIdx.x;
    if (b >= 81) {   // zero phase: blocks 81.. zero counts+cursor+flags
        int i = (b - 81) * 256 + threadIdx.x;
        int stride = (gridDim.x - 81) * 256;
        float4 z = make_float4(0.f, 0.f, 0.f, 0.f);
        for (; i < zn4; i += stride) zbase[i] = z;
        return;
    }
    int idx = b * 256 + threadIdx.x;
    if (idx < 16384) {
        int i = idx >> 7, j = idx & 127;
        float s = 0.f;
        for (int k = 0; k < 128; ++k) s = fmaf(Wx[i * 128 + k], Wm[k * 128 + j], s);
        int ks = i >> 5, r = i & 31, l4 = r >> 3, jj = r & 7;
        int ct = j >> 4, l15 = j & 15;
        Afrag[(ks * 8 + ct) * 512 + (l4 * 16 + l15) * 8 + jj] = f2bf(s);
    } else if (idx < 16384 + 4096) {
        int t = idx - 16384;
        int i = t >> 7, j = t & 127;
        float s = 0.f;
        for (int k = 0; k < 128; ++k) s = fmaf(We[i * 128 + k], Wm[(128 + k) * 128 + j], s);
        int l4 = i >> 3, jj = i & 7, ct = j >> 4, l15 = j & 15;
        Bfrag[ct * 512 + (l4 * 16 + l15) * 8 + jj] = f2bf(s);
    } else if (idx < 16384 + 4096 + 128) {
        int j = idx - 20480;
        float s = bm[j];
        for (int k = 0; k < 128; ++k) s = fmaf(bx[k], Wm[k * 128 + j], s);
        for (int k = 0; k < 128; ++k) s = fmaf(be[k], Wm[(128 + k) * 128 + j], s);
        c[j] = s;
    }
}

// ---------- K1: fused hist (blocks 0..2499) + node GEMM (blocks 2500..) ----------
__global__ __launch_bounds__(256, 4) void k_hist_node(
    const void* __restrict__ ei_raw, int* __restrict__ counts,
    const float* __restrict__ x, const u16* __restrict__ Afrag,
    const float* __restrict__ c, u16* __restrict__ n2b) {
    __shared__ u16 x_s[XNS * XRS];
    int b = blockIdx.x;
    int tid = threadIdx.x;
    if (b < NBLK_H) {   // ---- hist ----
        int e = b * 256 + tid;
        if (e >= N_EDGES) return;
        int dst;
        if (detect32((const int*)ei_raw)) {
            dst = ((const int*)ei_raw)[N_EDGES + e];
        } else {
            dst = (int)((const long long*)ei_raw)[N_EDGES + e];
        }
        atomicAdd(&counts[dst], 1);
        return;
    }
    // ---- node GEMM (r16-proven) ----
    int nb = (b - NBLK_H) * XNS;
    {
        int row = tid >> 2, q = tid & 3;
        int node = nb + row;
        u16* wp = &x_s[row * XRS + q * 32];
        if (node < N_NODES) {
            const float4* src = (const float4*)(x + (size_t)node * 128 + q * 32);
#pragma unroll
            for (int i = 0; i < 8; ++i) {
                float4 v = src[i];
                *(uint2*)(wp + i * 4) =
                    make_uint2(f2bf2(v.x, v.y), f2bf2(v.z, v.w));
            }
        } else {
#pragma unroll
            for (int i = 0; i < 8; ++i)
                *(uint2*)(wp + i * 4) = make_uint2(0u, 0u);
        }
    }
    int lane = tid & 63, wv = tid >> 6;
    int l15 = lane & 15, l4 = lane >> 4;
    f32x4 acc[8];
#pragma unroll
    for (int ct = 0; ct < 8; ++ct) {
        float cv = c[ct * 16 + l15];
        acc[ct] = (f32x4){cv, cv, cv, cv};
    }
    __syncthreads();
    int w16 = wv * 16;
#pragma unroll
    for (int ks = 0; ks < 4; ++ks) {
        bf16x8 af = *(const bf16x8*)(&x_s[(w16 + l15) * XRS + ks * 32 + l4 * 8]);
#pragma unroll
        for (int ct = 0; ct < 8; ++ct) {
            bf16x8 bf = *(const bf16x8*)(Afrag + (size_t)(ks * 8 + ct) * 512 + lane * 8);
            acc[ct] = __builtin_amdgcn_mfma_f32_16x16x32_bf16(af, bf, acc[ct], 0, 0, 0);
        }
    }
    int node0 = nb + w16 + l4 * 4;
#pragma unroll
    for (int ct = 0; ct < 8; ++ct) {
        int col = ct * 16 + l15;
#pragma unroll
        for (int r = 0; r < 4; ++r) {
            int node = node0 + r;
            if (node < N_NODES) n2b[(size_t)node * 128 + col] = f2bf(acc[ct][r]);
        }
    }
}

// ---------- scan A: per-1024-chunk sums ----------
__global__ __launch_bounds__(256) void k_scan_a(
    const int* __restrict__ counts, int* __restrict__ bsum) {
    __shared__ int L[256];
    int b = blockIdx.x, t = threadIdx.x;
    int base = b * SCAN_CHUNK + t * 4;
    int s = 0;
#pragma unroll
    for (int r = 0; r < 4; ++r) {
        int i = base + r;
        if (i < N_NODES) s += counts[i];
    }
    L[t] = s;
    __syncthreads();
    for (int h = 128; h > 0; h >>= 1) {
        if (t < h) L[t] += L[t + h];
        __syncthreads();
    }
    if (t == 0) bsum[b] = L[0];
}

// ---------- scan C (absorbs scan B + boundary-agg zero, 64-edge segments) ----------
__global__ __launch_bounds__(256) void k_scan_c(
    const int* __restrict__ counts, const int* __restrict__ bsum,
    int* __restrict__ offsets, float* __restrict__ agg) {
    __shared__ int L[256];
    __shared__ int BS[128];
    int b = blockIdx.x, t = threadIdx.x;
    if (t < NB_SCAN) BS[t] = bsum[t];
    int base = b * SCAN_CHUNK + t * 4;
    int c0 = 0, c1 = 0, c2 = 0, c3 = 0;
    if (base + 0 < N_NODES) c0 = counts[base + 0];
    if (base + 1 < N_NODES) c1 = counts[base + 1];
    if (base + 2 < N_NODES) c2 = counts[base + 2];
    if (base + 3 < N_NODES) c3 = counts[base + 3];
    L[t] = c0 + c1 + c2 + c3;
    __syncthreads();
    if (t == 0) {
        int run = 0;
        for (int i = 0; i < b; ++i) run += BS[i];   // block offset
        for (int i = 0; i < 256; ++i) { int tmp = L[i]; L[i] = run; run += tmp; }
    }
    __syncthreads();
    int o = L[t];
    int oo[4] = {o, o + c0, o + c0 + c1, o + c0 + c1 + c2};
    int cc[4] = {c0, c1, c2, c3};
#pragma unroll
    for (int r = 0; r < 4; ++r) {
        int node = base + r;
        if (node >= N_NODES) break;
        offsets[node] = oo[r];
        int cn = cc[r];
        if (cn > 0) {
            int oe = oo[r] + cn;
            bool bnd = ((oo[r] & 63) == 0) || ((oe & 63) == 0) ||
                       ((oo[r] >> 6) != ((oe - 1) >> 6));
            if (bnd) {
                float4* ap = (float4*)(agg + (size_t)node * 128);
                float4 z = make_float4(0.f, 0.f, 0.f, 0.f);
#pragma unroll
                for (int q = 0; q < 32; ++q) ap[q] = z;
            }
        }
    }
}

// ---------- scatter: packed (perm,src,dst) int4, one scattered store ----------
__global__ __launch_bounds__(256) void k_scatter(
    const void* __restrict__ ei_raw, const int* __restrict__ offsets,
    int* __restrict__ cursor, int4* __restrict__ esd) {
    int e = blockIdx.x * 256 + threadIdx.x;
    if (e >= N_EDGES) return;
    int src, dst;
    if (detect32((const int*)ei_raw)) {
        src = ((const int*)ei_raw)[e];
        dst = ((const int*)ei_raw)[N_EDGES + e];
    } else {
        src = (int)((const long long*)ei_raw)[e];
        dst = (int)((const long long*)ei_raw)[N_EDGES + e];
    }
    int pos = offsets[dst] + atomicAdd(&cursor[dst], 1);
    esd[pos] = make_int4(e, src, dst, 0);
}

// ---------- K2: edge MLP via MFMA + col-major LDS msg + vectorized sweep ----------
// (r14/r16-proven structure; esd int4 replaces perm/src_s/dst_s)
__global__ __launch_bounds__(256, 4) void k_edge_mlp(
    const float* __restrict__ ea, const int4* __restrict__ esd,
    const u16* __restrict__ Bfrag, const u16* __restrict__ n2b,
    float* __restrict__ agg, u8* __restrict__ flags,
    const float* __restrict__ beta, float* __restrict__ out) {
    __shared__ union ShMem {
        u16 ea[EPB * EAS];      // 10240 B (staging phase)
        u16 msg[128 * MTS];     // 34816 B (message phase, col-major)
    } sh;
    __shared__ __align__(16) int src_l[EPB];
    __shared__ __align__(16) int dst_l[EPB];
    int tid = threadIdx.x;
    int base = blockIdx.x * EPB;
    if (tid < EPB) {
        int4 v = esd[base + tid];
        src_l[tid] = v.y;
        dst_l[tid] = v.z;
    }
    {   // stage ea rows f32 -> bf16 (hardware packed cvt)
        int row = tid >> 1, q = tid & 1;
        int p = esd[base + row].x;   // pairs share; L1 broadcast
        const float4* s4 = (const float4*)(ea + (size_t)p * 32 + q * 16);
        float4 v0 = s4[0], v1 = s4[1], v2 = s4[2], v3 = s4[3];
        u16* wp = &sh.ea[row * EAS + q * 16];
        *(uint2*)(wp + 0)  = make_uint2(f2bf2(v0.x, v0.y), f2bf2(v0.z, v0.w));
        *(uint2*)(wp + 4)  = make_uint2(f2bf2(v1.x, v1.y), f2bf2(v1.z, v1.w));
        *(uint2*)(wp + 8)  = make_uint2(f2bf2(v2.x, v2.y), f2bf2(v2.z, v2.w));
        *(uint2*)(wp + 12) = make_uint2(f2bf2(v3.x, v3.y), f2bf2(v3.z, v3.w));
    }
    int lane = tid & 63, wv = tid >> 6;
    int l15 = lane & 15, l4 = lane >> 4;
    bf16x8 bfr[8];
#pragma unroll
    for (int ct = 0; ct < 8; ++ct)
        bfr[ct] = *(const bf16x8*)(Bfrag + ct * 512 + lane * 8);
    float rb = fmaxf(beta[0], 0.f);
    __syncthreads();   // ea + src/dst_l visible
    bf16x8 af0 = *(const bf16x8*)(&sh.ea[(wv * 32 + 0  + l15) * EAS + l4 * 8]);
    bf16x8 af1 = *(const bf16x8*)(&sh.ea[(wv * 32 + 16 + l15) * EAS + l4 * 8]);
    // batched n2b gathers (placement proven r11/r14)
    u16 nv0[8][4], nv1[8][4];
#pragma unroll
    for (int r = 0; r < 4; ++r) {
        const u16* nr = n2b + (size_t)src_l[wv * 32 + 0 * 16 + l4 * 4 + r] * 128 + l15;
#pragma unroll
        for (int ct = 0; ct < 8; ++ct) nv0[ct][r] = nr[ct * 16];
    }
#pragma unroll
    for (int r = 0; r < 4; ++r) {
        const u16* nr = n2b + (size_t)src_l[wv * 32 + 1 * 16 + l4 * 4 + r] * 128 + l15;
#pragma unroll
        for (int ct = 0; ct < 8; ++ct) nv1[ct][r] = nr[ct * 16];
    }
    __syncthreads();   // all waves done reading sh.ea -> safe to write sh.msg

#pragma unroll
    for (int et = 0; et < 2; ++et) {
        bf16x8 af = et ? af1 : af0;
        int e0 = wv * 32 + et * 16 + l4 * 4;
#pragma unroll
        for (int ct = 0; ct < 8; ++ct) {
            f32x4 acc = {0.f, 0.f, 0.f, 0.f};
            acc = __builtin_amdgcn_mfma_f32_16x16x32_bf16(af, bfr[ct], acc, 0, 0, 0);
            int col = ct * 16 + l15;
            float m0 = acc[0] + bf2f(et ? nv1[ct][0] : nv0[ct][0]);
            float m1 = acc[1] + bf2f(et ? nv1[ct][1] : nv0[ct][1]);
            float m2 = acc[2] + bf2f(et ? nv1[ct][2] : nv0[ct][2]);
            float m3 = acc[3] + bf2f(et ? nv1[ct][3] : nv0[ct][3]);
            m0 = fmaxf(m0, 0.01f * m0);   // leaky: max(x, 0.01x)
            m1 = fmaxf(m1, 0.01f * m1);
            m2 = fmaxf(m2, 0.01f * m2);
            m3 = fmaxf(m3, 0.01f * m3);
            u32 w01 = f2bf2(m0, m1);
            u32 w23 = f2bf2(m2, m3);
            *(uint2*)(&sh.msg[col * MTS + e0]) = make_uint2(w01, w23);
        }
    }
    __syncthreads();

    int c = tid & 127, h = tid >> 7;
    const u16* mrow = &sh.msg[c * MTS + h * 64];
    const int4* drow = (const int4*)(dst_l + h * 64);
    float acc = 0.f;
    int cur = dst_l[h * 64];
    int nflush = 0;
#pragma unroll 1
    for (int g = 0; g < 8; ++g) {
        bf16x8 mv = *(const bf16x8*)(mrow + g * 8);
        int4 da = drow[g * 2], db = drow[g * 2 + 1];
        int dd[8] = {da.x, da.y, da.z, da.w, db.x, db.y, db.z, db.w};
#pragma unroll
        for (int j = 0; j < 8; ++j) {
            int d = dd[j];
            if (d != cur) {
                if (nflush) {   // run strictly inside segment: node complete
                    out[(size_t)cur * 128 + c] = sigrb(acc, rb);
                    if (c == 0) flags[cur] = 1;
                } else {        // touches segment start
                    unsafeAtomicAdd(agg + (size_t)cur * 128 + c, acc);
                }
                ++nflush;
                acc = 0.f;
                cur = d;
            }
            acc += bf2f((u16)mv[j]);
        }
    }
    unsafeAtomicAdd(agg + (size_t)cur * 128 + c, acc);  // touches segment end
}

// ---------- K3: finish boundary + zero-degree nodes ----------
__global__ __launch_bounds__(256) void k_final(
    const float* __restrict__ agg, const u8* __restrict__ flags,
    const int* __restrict__ counts, const float* __restrict__ beta,
    float4* __restrict__ out) {
    float rb = fmaxf(beta[0], 0.f);
    float hb = 0.5f * rb;
    int i = blockIdx.x * 256 + threadIdx.x;
    int stride = gridDim.x * 256;
    const float4* a4 = (const float4*)agg;
    const int n4 = N_NODES * 32;   // 32 float4 per node
    for (; i < n4; i += stride) {
        int node = i >> 5;
        if (flags[node]) continue;           // interior: out already written
        if (counts[node] == 0) {             // zero-degree: sigmoid(0)*rb
            out[i] = make_float4(hb, hb, hb, hb);
            continue;
        }
        float4 v = a4[i];
        float4 r;
        r.x = sigrb(v.x, rb);
        r.y = sigrb(v.y, rb);
        r.z = sigrb(v.z, rb);
        r.w = sigrb(v.w, rb);
        out[i] = r;
    }
}

// ---------- launch ----------
extern "C" void kernel_launch(void* const* d_in, const int* in_sizes, int n_in,
                              void* d_out, int out_size, void* d_ws, size_t ws_size,
                              hipStream_t stream) {
    const float* x    = (const float*)d_in[0];
    const float* ea   = (const float*)d_in[1];
    const float* Wx   = (const float*)d_in[2];
    const float* bx   = (const float*)d_in[3];
    const float* We   = (const float*)d_in[4];
    const float* be   = (const float*)d_in[5];
    const float* Wm   = (const float*)d_in[6];
    const float* bm   = (const float*)d_in[7];
    const float* beta = (const float*)d_in[8];
    const void*  ei   = d_in[9];

    // ws layout (byte offsets):
    //   c @0 (512), Bfrag @512 (8192), Afrag @8704 (32768) -> 41472
    //   counts @41472 (400000), cursor @441472 (400000),
    //   flags @841472 (102400), agg @943872 (51200000) -> 52143872
    //   bsum @52143872 (512), offs @52144896 (400000)
    //   esd @52544896 (10240000: int4 perm/src/dst)
    //   n2b @62784896 (25600000) -> 88384896
    if (ws_size < (size_t)88384896) return;

    char* ws = (char*)d_ws;
    float* c      = (float*)(ws);
    u16*   Bfrag  = (u16*)(ws + 512);
    u16*   Afrag  = (u16*)(ws + 8704);
    int*   counts = (int*)(ws + 41472);
    int*   cursor = (int*)(ws + 441472);
    u8*    flags  = (u8*)(ws + 841472);
    float* agg    = (float*)(ws + 943872);
    int*   bsum   = (int*)(ws + 52143872);
    int*   offs   = (int*)(ws + 52144896);
    int4*  esd    = (int4*)(ws + 52544896);
    u16*   n2b    = (u16*)(ws + 62784896);

    // fold + zero counts/cursor/flags (902,400 B = 56,400 float4)
    k_fold_zero<<<81 + 256, 256, 0, stream>>>(Wx, bx, We, be, Wm, bm,
                                              Afrag, Bfrag, c,
                                              (float4*)(ws + 41472), 56400);
    // fused: hist (2500 blocks) + node GEMM (1563 blocks)
    k_hist_node<<<NBLK_H + NBLK_N, 256, 0, stream>>>(ei, counts, x, Afrag, c, n2b);
    k_scan_a<<<NB_SCAN, 256, 0, stream>>>(counts, bsum);
    k_scan_c<<<NB_SCAN, 256, 0, stream>>>(counts, bsum, offs, agg);
    k_scatter<<<2500, 256, 0, stream>>>(ei, offs, cursor, esd);
    k_edge_mlp<<<NBLK_E, 256, 0, stream>>>(ea, esd, Bfrag, n2b,
                                           agg, flags, beta, (float*)d_out);
    k_final<<<2048, 256, 0, stream>>>(agg, flags, counts, beta, (float4*)d_out);
}